// Round 5
// baseline (19167.270 us; speedup 1.0000x reference)
//
#include <hip/hip_runtime.h>
#include <math.h>

#define S_LEN 4096
#define HID   2048
#define NBLK  256
#define NTHR  512   // 8 waves/block, 1 block/CU

typedef unsigned long long u64;
typedef float v2f __attribute__((ext_vector_type(2)));

// R5 = R4's tagged-data dataflow sync + shortened in-step serial chain:
//  - tagged hx: {f32 value | u32 epoch} in one 8B relaxed agent-scope atomic.
//    No fences, no RMWs, single coherence hop. Exact-tag match (1..4097) can
//    never alias the 0xAA ws poison -> no memset, no init race.
//  - per-wave gate ownership: wave wv owns hidden unit b*8+wv and ALL 4 of its
//    gate columns. After the in-wave shuffle reduce, lane 0 does the cell math
//    and publishes. Drops the 2nd __syncthreads + gates_lds round-trip of R4.
//  - hx_lds double-buffered by step parity (single sync per step; lap-safe).
//  - float2 accumulators via __builtin_elementwise_fma -> v_pk_fma_f32
//    (halves FMA issue: 64 packed vs 128 scalar per lane per step).
//  - fast activations: sigmoid = 1/(1+__expf(-x)); tanh = copysign(1-2/(e^{2|x|}+1)).

__device__ __forceinline__ float fsig(float x) {
    return 1.0f / (1.0f + __expf(-x));
}
__device__ __forceinline__ float ftanh(float x) {
    float e = __expf(2.0f * fabsf(x));       // >= 1; inf for large |x| -> r = 1
    float r = 1.0f - 2.0f / (e + 1.0f);
    return copysignf(r, x);
}

__global__ __launch_bounds__(NTHR, 2)
void qlstm_persistent(const float* __restrict__ inp,     // (S,1,4)
                      const float* __restrict__ conv_w,  // (4)
                      const float* __restrict__ conv_b,  // (1)
                      const float* __restrict__ Wg,      // (2049, 8192) row-major
                      const float* __restrict__ bg,      // (8192)
                      float* __restrict__ out,           // S*H + H + H
                      float* __restrict__ ws)            // scratch (poison 0xAA ok)
{
    const int b   = blockIdx.x;
    const int tid = threadIdx.x;
    const int l   = tid & 63;
    const int wv  = tid >> 6;

    u64* tb0 = (u64*)ws;            // [HID] tagged hx, parity 0
    u64* tb1 = tb0 + HID + 16;      // [HID] tagged hx, parity 1 (line-padded)

    __shared__ __align__(16) float hx_lds[2][HID];   // step-parity double buffer
    __shared__ __align__(16) float conv_lds[S_LEN];

    // ---------------- init phase ----------------
    {
        const float cw0 = conv_w[0], cw1 = conv_w[1], cw2 = conv_w[2], cw3 = conv_w[3];
        const float cb  = conv_b[0];
        for (int g = tid; g < S_LEN; g += NTHR) {
            float4 x = ((const float4*)inp)[g];
            float v = x.x*cw0 + x.y*cw1 + x.z*cw2 + x.w*cw3 + cb;
            conv_lds[g] = fsig(v);
        }
    }

    // wave wv owns hidden unit u = b*8 + wv; its 4 gate columns (f|i|g|o):
    const int unit = b * 8 + wv;
    int jcol[4];
    #pragma unroll
    for (int c = 0; c < 4; ++c) jcol[c] = (c << 11) + unit;   // c*2048 + unit

    // wave-uniform row-0 weights + biases (scalar regs)
    float cw_r[4], cb_r[4];
    #pragma unroll
    for (int c = 0; c < 4; ++c) {
        cw_r[c] = Wg[jcol[c]];
        cb_r[c] = bg[jcol[c]];
    }

    // persistent W registers, packed as float2 pairs matching the float4 LDS reads:
    // lane l consumes hx elements e = 4l + 256j + r (j=0..7, r=0..3)
    // wreg2[c][2j+p] = { W[1+4l+256j+2p][jcol[c]], W[1+4l+256j+2p+1][jcol[c]] }
    v2f wreg2[4][16];
    #pragma unroll
    for (int j = 0; j < 8; ++j)
        #pragma unroll
        for (int p = 0; p < 2; ++p) {
            const float* r0 = Wg + (size_t)(1 + 4*l + 256*j + 2*p) * 8192;
            const float* r1 = r0 + 8192;
            #pragma unroll
            for (int c = 0; c < 4; ++c)
                wreg2[c][2*j + p] = (v2f){ r0[jcol[c]], r1[jcol[c]] };
        }

    float cx = 0.0f;                    // live in lane 0 of each wave
    const int ebase = (wv << 8) + l;    // this thread's tagged-entry base

    // publish hx_0 = 0 with tag 1 (single 8B atomic; tag travels with value)
    if (tid < 8)
        __hip_atomic_store(&tb0[b * 8 + tid], (u64)1 << 32,
                           __ATOMIC_RELAXED, __HIP_MEMORY_SCOPE_AGENT);

    // ---------------- recurrence ----------------
    for (int t = 0; t < S_LEN; ++t) {
        const unsigned want = (unsigned)(t + 1);
        u64* tb = (t & 1) ? tb1 : tb0;  // hx_t lives here, tag t+1
        u64* tn = (t & 1) ? tb0 : tb1;  // hx_{t+1} goes here, tag t+2
        float* hbuf = hx_lds[t & 1];

        // poll own 4 tagged entries (pipelined; retries touch only stragglers)
        u64 v0 = 0, v1 = 0, v2 = 0, v3 = 0;
        unsigned pend = 0xFu;
        do {
            if (pend & 1u) v0 = __hip_atomic_load(&tb[ebase      ], __ATOMIC_RELAXED, __HIP_MEMORY_SCOPE_AGENT);
            if (pend & 2u) v1 = __hip_atomic_load(&tb[ebase +  64], __ATOMIC_RELAXED, __HIP_MEMORY_SCOPE_AGENT);
            if (pend & 4u) v2 = __hip_atomic_load(&tb[ebase + 128], __ATOMIC_RELAXED, __HIP_MEMORY_SCOPE_AGENT);
            if (pend & 8u) v3 = __hip_atomic_load(&tb[ebase + 192], __ATOMIC_RELAXED, __HIP_MEMORY_SCOPE_AGENT);
            if ((unsigned)(v0 >> 32) == want) pend &= ~1u;
            if ((unsigned)(v1 >> 32) == want) pend &= ~2u;
            if ((unsigned)(v2 >> 32) == want) pend &= ~4u;
            if ((unsigned)(v3 >> 32) == want) pend &= ~8u;
        } while (pend);
        hbuf[ebase      ] = __uint_as_float((unsigned)v0);
        hbuf[ebase +  64] = __uint_as_float((unsigned)v1);
        hbuf[ebase + 128] = __uint_as_float((unsigned)v2);
        hbuf[ebase + 192] = __uint_as_float((unsigned)v3);
        __syncthreads();                       // the ONLY per-step block sync

        const float4* hl = (const float4*)hbuf;
        v2f a0 = {0.f, 0.f}, a1 = {0.f, 0.f}, a2 = {0.f, 0.f}, a3 = {0.f, 0.f};
        #pragma unroll
        for (int j = 0; j < 8; ++j) {
            float4 h = hl[l + 64*j];           // ds_read_b128, conflict-free
            v2f h01 = { h.x, h.y };
            v2f h23 = { h.z, h.w };
            a0 = __builtin_elementwise_fma(h01, wreg2[0][2*j  ], a0);
            a1 = __builtin_elementwise_fma(h01, wreg2[1][2*j  ], a1);
            a2 = __builtin_elementwise_fma(h01, wreg2[2][2*j  ], a2);
            a3 = __builtin_elementwise_fma(h01, wreg2[3][2*j  ], a3);
            a0 = __builtin_elementwise_fma(h23, wreg2[0][2*j+1], a0);
            a1 = __builtin_elementwise_fma(h23, wreg2[1][2*j+1], a1);
            a2 = __builtin_elementwise_fma(h23, wreg2[2][2*j+1], a2);
            a3 = __builtin_elementwise_fma(h23, wreg2[3][2*j+1], a3);
        }
        float acc0 = a0.x + a0.y;
        float acc1 = a1.x + a1.y;
        float acc2 = a2.x + a2.y;
        float acc3 = a3.x + a3.y;
        #pragma unroll
        for (int off = 32; off; off >>= 1) {
            acc0 += __shfl_down(acc0, off, 64);
            acc1 += __shfl_down(acc1, off, 64);
            acc2 += __shfl_down(acc2, off, 64);
            acc3 += __shfl_down(acc3, off, 64);
        }

        // cell math + publish: lane 0 of EACH wave, fully parallel across waves
        if (l == 0) {
            float ct = conv_lds[t];
            float f  = fsig (acc0 + ct*cw_r[0] + cb_r[0]);
            float ii = fsig (acc1 + ct*cw_r[1] + cb_r[1]);
            float gv = ftanh(acc2 + ct*cw_r[2] + cb_r[2]);
            float o  = fsig (acc3 + ct*cw_r[3] + cb_r[3]);
            cx = f * cx + ii * gv;
            float hx = o * ftanh(cx);
            // publish: one 8B atomic carrying {value, tag t+2}
            __hip_atomic_store(&tn[unit],
                               ((u64)(unsigned)(t + 2) << 32) | (u64)__float_as_uint(hx),
                               __ATOMIC_RELAXED, __HIP_MEMORY_SCOPE_AGENT);
            // out[] store off the critical path (after the publish)
            out[(size_t)t * HID + unit] = hx;
            if (t == S_LEN - 1) {
                out[(size_t)S_LEN * HID + unit]       = hx;   // final hx
                out[(size_t)S_LEN * HID + HID + unit] = cx;   // final cx
            }
        }
    }
}

extern "C" void kernel_launch(void* const* d_in, const int* in_sizes, int n_in,
                              void* d_out, int out_size, void* d_ws, size_t ws_size,
                              hipStream_t stream) {
    const float* inp    = (const float*)d_in[0];
    const float* conv_w = (const float*)d_in[1];
    const float* conv_b = (const float*)d_in[2];
    const float* Wg     = (const float*)d_in[3];
    const float* bg     = (const float*)d_in[4];
    float* out = (float*)d_out;
    float* ws  = (float*)d_ws;

    // no memset needed: exact-match tags (1..4097) can never alias 0xAA poison

    void* args[] = {(void*)&inp, (void*)&conv_w, (void*)&conv_b,
                    (void*)&Wg, (void*)&bg, (void*)&out, (void*)&ws};
    hipLaunchCooperativeKernel((void*)qlstm_persistent,
                               dim3(NBLK), dim3(NTHR), args, 0, stream);
}

// Round 6
// 13568.117 us; speedup vs baseline: 1.4127x; 1.4127x over previous
//
#include <hip/hip_runtime.h>
#include <math.h>

#define S_LEN 4096
#define HID   2048
#define NBLK  256
#define NTHR  512          // 8 waves/block, 1 block/CU
#define RSTRIDE (2*HID+16) // u64s per replica region (2 parities + pad, 16B-aligned)

typedef unsigned long long u64;
typedef float v2f __attribute__((ext_vector_type(2)));
typedef unsigned int v4u __attribute__((ext_vector_type(4)));

// R6 = R4 structure (tagged-data dataflow; wave 0 computes + publishes all 8 units
// as one coalesced burst; two block syncs) + anti-hot-line sync:
//  - 16B polls: one global_load_dwordx4 sc0 sc1 (agent-scope bypass, same encoding
//    LLVM uses for agent atomic loads) fetches TWO {f32 val | u32 tag} entries.
//    Each 8B entry's tag is validated independently -> torn pairs are harmless.
//  - replicated publish: producers store their 8 entries into nrep (<=8) replica
//    regions; consumer block b polls only region b&(nrep-1). Spreads poll traffic
//    across 8x more IC lines, cuts per-line consumers 256 -> 32.
//  - fast activations + packed v_pk_fma_f32 (validated in R5: absmax unchanged).
//  - exact-tag match (1..4097) can never alias 0xAA ws poison -> no memset.

__device__ __forceinline__ float fsig(float x) {
    return 1.0f / (1.0f + __expf(-x));
}
__device__ __forceinline__ float ftanh(float x) {
    float e = __expf(2.0f * fabsf(x));       // >=1; inf for large |x| -> r = 1
    float r = 1.0f - 2.0f / (e + 1.0f);
    return copysignf(r, x);
}

// agent-scope (L1+L2 bypass) 16B loads of two tagged entries
__device__ __forceinline__ void ld16x2(const u64* pa, const u64* pb, v4u& A, v4u& B) {
    asm volatile("global_load_dwordx4 %0, %2, off sc0 sc1\n\t"
                 "global_load_dwordx4 %1, %3, off sc0 sc1\n\t"
                 "s_waitcnt vmcnt(0)"
                 : "=&v"(A), "=&v"(B) : "v"(pa), "v"(pb) : "memory");
}
__device__ __forceinline__ v4u ld16(const u64* p) {
    v4u r;
    asm volatile("global_load_dwordx4 %0, %1, off sc0 sc1\n\t"
                 "s_waitcnt vmcnt(0)"
                 : "=&v"(r) : "v"(p) : "memory");
    return r;
}

__global__ __launch_bounds__(NTHR, 2)
void qlstm_persistent(const float* __restrict__ inp,     // (S,1,4)
                      const float* __restrict__ conv_w,  // (4)
                      const float* __restrict__ conv_b,  // (1)
                      const float* __restrict__ Wg,      // (2049, 8192) row-major
                      const float* __restrict__ bg,      // (8192)
                      float* __restrict__ out,           // S*H + H + H
                      float* __restrict__ ws,            // scratch (poison 0xAA ok)
                      int nmask)                         // nrep-1 (0,1,3,7)
{
    const int b   = blockIdx.x;
    const int tid = threadIdx.x;
    const int l   = tid & 63;
    const int wv  = tid >> 6;

    u64* tb = (u64*)ws;     // [nrep][RSTRIDE]: per region, parity0 @0, parity1 @HID

    __shared__ __align__(16) float hx_lds[HID];
    __shared__ __align__(16) float conv_lds[S_LEN];
    __shared__ float gates_lds[32];

    // ---------------- init phase ----------------
    {
        const float cw0 = conv_w[0], cw1 = conv_w[1], cw2 = conv_w[2], cw3 = conv_w[3];
        const float cb  = conv_b[0];
        for (int g = tid; g < S_LEN; g += NTHR) {
            float4 x = ((const float4*)inp)[g];
            conv_lds[g] = fsig(x.x*cw0 + x.y*cw1 + x.z*cw2 + x.w*cw3 + cb);
        }
    }

    // wave wv owns gate columns cgi = 4wv+c; cgi -> gate = cgi>>3, unit mi = cgi&7
    int jcol[4];
    #pragma unroll
    for (int c = 0; c < 4; ++c) {
        int cgi  = 4*wv + c;
        jcol[c]  = ((cgi >> 3) << 11) + (b * 8 + (cgi & 7));
    }

    // cell-phase constants in registers (meaningful in lanes tid<8, wave 0)
    float cw_reg[4], cb_reg[4];
    {
        int u8 = b * 8 + (tid & 7);
        #pragma unroll
        for (int c = 0; c < 4; ++c) {
            cw_reg[c] = Wg[(c << 11) + u8];
            cb_reg[c] = bg[(c << 11) + u8];
        }
    }

    // persistent packed W: lane l consumes hx elements 4l+256j+r (j=0..7, r=0..3)
    // wreg2[c][2j+p] = { W[1+4l+256j+2p][jcol[c]], W[1+4l+256j+2p+1][jcol[c]] }
    v2f wreg2[4][16];
    #pragma unroll
    for (int j = 0; j < 8; ++j)
        #pragma unroll
        for (int p = 0; p < 2; ++p) {
            const float* r0 = Wg + (size_t)(1 + 4*l + 256*j + 2*p) * 8192;
            const float* r1 = r0 + 8192;
            #pragma unroll
            for (int c = 0; c < 4; ++c)
                wreg2[c][2*j + p] = (v2f){ r0[jcol[c]], r1[jcol[c]] };
        }

    float cx = 0.0f;                       // live in lanes tid<8
    const int unit = b * 8 + (tid & 7);    // hidden unit for tid<8
    const int reg  = b & nmask;            // this block's poll region

    // publish hx_0 = 0 with tag 1 into every replica region
    if (tid < 8) {
        u64 pub = (u64)1 << 32;
        for (int r = 0; r <= nmask; ++r)
            __hip_atomic_store(&tb[(size_t)r*RSTRIDE + unit], pub,
                               __ATOMIC_RELAXED, __HIP_MEMORY_SCOPE_AGENT);
    }

    // thread's two entry-pairs within the block's region (entries 2l,2l+1 etc.)
    const int pair0 = (wv << 8) + 2*l;     // entries pair0, pair0+1
    // pair1 = pair0 + 128

    // ---------------- recurrence ----------------
    for (int t = 0; t < S_LEN; ++t) {
        const unsigned want = (unsigned)(t + 1);
        const u64* base = tb + (size_t)reg*RSTRIDE + (size_t)(t & 1)*HID;
        u64*       nbuf = tb + (size_t)((t + 1) & 1)*HID;   // region 0; +r*RSTRIDE
        const u64* p0 = base + pair0;
        const u64* p1 = base + pair0 + 128;

        // poll 4 entries as two 16B loads; retries touch only pending pairs
        v4u A, B;
        ld16x2(p0, p1, A, B);
        unsigned pend = 3u;
        for (;;) {
            if ((pend & 1u) && A.y == want && A.w == want) pend &= ~1u;
            if ((pend & 2u) && B.y == want && B.w == want) pend &= ~2u;
            if (!pend) break;
            if (pend == 3u)      ld16x2(p0, p1, A, B);
            else if (pend & 1u)  A = ld16(p0);
            else                 B = ld16(p1);
        }
        ((float2*)hx_lds)[(wv << 7) + l] =
            (float2){ __uint_as_float(A.x), __uint_as_float(A.z) };
        ((float2*)hx_lds)[(wv << 7) + 64 + l] =
            (float2){ __uint_as_float(B.x), __uint_as_float(B.z) };
        __syncthreads();                       // A: hx_lds complete

        const float4* hl = (const float4*)hx_lds;
        v2f a0 = {0.f, 0.f}, a1 = {0.f, 0.f}, a2 = {0.f, 0.f}, a3 = {0.f, 0.f};
        #pragma unroll
        for (int j = 0; j < 8; ++j) {
            float4 h = hl[l + 64*j];           // ds_read_b128, conflict-free
            v2f h01 = { h.x, h.y };
            v2f h23 = { h.z, h.w };
            a0 = __builtin_elementwise_fma(h01, wreg2[0][2*j  ], a0);
            a1 = __builtin_elementwise_fma(h01, wreg2[1][2*j  ], a1);
            a2 = __builtin_elementwise_fma(h01, wreg2[2][2*j  ], a2);
            a3 = __builtin_elementwise_fma(h01, wreg2[3][2*j  ], a3);
            a0 = __builtin_elementwise_fma(h23, wreg2[0][2*j+1], a0);
            a1 = __builtin_elementwise_fma(h23, wreg2[1][2*j+1], a1);
            a2 = __builtin_elementwise_fma(h23, wreg2[2][2*j+1], a2);
            a3 = __builtin_elementwise_fma(h23, wreg2[3][2*j+1], a3);
        }
        float acc0 = a0.x + a0.y;
        float acc1 = a1.x + a1.y;
        float acc2 = a2.x + a2.y;
        float acc3 = a3.x + a3.y;
        #pragma unroll
        for (int off = 32; off; off >>= 1) {
            acc0 += __shfl_down(acc0, off, 64);
            acc1 += __shfl_down(acc1, off, 64);
            acc2 += __shfl_down(acc2, off, 64);
            acc3 += __shfl_down(acc3, off, 64);
        }
        if (l == 0) {
            gates_lds[4*wv + 0] = acc0;
            gates_lds[4*wv + 1] = acc1;
            gates_lds[4*wv + 2] = acc2;
            gates_lds[4*wv + 3] = acc3;
        }
        __syncthreads();                       // B: gates complete
        // waves 1..7 skip the tail below and immediately poll step t+1

        if (tid < 8) {
            float ct = conv_lds[t];
            float f  = fsig (gates_lds[tid]      + ct*cw_reg[0] + cb_reg[0]);
            float ii = fsig (gates_lds[8 + tid]  + ct*cw_reg[1] + cb_reg[1]);
            float gv = ftanh(gates_lds[16 + tid] + ct*cw_reg[2] + cb_reg[2]);
            float o  = fsig (gates_lds[24 + tid] + ct*cw_reg[3] + cb_reg[3]);
            cx = f * cx + ii * gv;
            float hx = o * ftanh(cx);
            // publish to every replica region: 8B atomics, 8 lanes -> 64B bursts
            u64 pub = ((u64)(unsigned)(t + 2) << 32) | (u64)__float_as_uint(hx);
            for (int r = 0; r <= nmask; ++r)
                __hip_atomic_store(&nbuf[(size_t)r*RSTRIDE + unit], pub,
                                   __ATOMIC_RELAXED, __HIP_MEMORY_SCOPE_AGENT);
            // out[] store off the critical path (after the publish)
            out[(size_t)t * HID + unit] = hx;
            if (t == S_LEN - 1) {
                out[(size_t)S_LEN * HID + unit]       = hx;   // final hx
                out[(size_t)S_LEN * HID + HID + unit] = cx;   // final cx
            }
        }
    }
}

extern "C" void kernel_launch(void* const* d_in, const int* in_sizes, int n_in,
                              void* d_out, int out_size, void* d_ws, size_t ws_size,
                              hipStream_t stream) {
    const float* inp    = (const float*)d_in[0];
    const float* conv_w = (const float*)d_in[1];
    const float* conv_b = (const float*)d_in[2];
    const float* Wg     = (const float*)d_in[3];
    const float* bg     = (const float*)d_in[4];
    float* out = (float*)d_out;
    float* ws  = (float*)d_ws;

    // replica count from workspace size (power of 2, <= 8)
    size_t rbytes = (size_t)RSTRIDE * 8;
    int nrep = 1;
    while (nrep < 8 && (size_t)(nrep * 2) * rbytes <= ws_size) nrep *= 2;
    int nmask = nrep - 1;

    void* args[] = {(void*)&inp, (void*)&conv_w, (void*)&conv_b,
                    (void*)&Wg, (void*)&bg, (void*)&out, (void*)&ws, (void*)&nmask};
    hipLaunchCooperativeKernel((void*)qlstm_persistent,
                               dim3(NBLK), dim3(NTHR), args, 0, stream);
}

// Round 7
// 13382.356 us; speedup vs baseline: 1.4323x; 1.0139x over previous
//
#include <hip/hip_runtime.h>
#include <math.h>

#define S_LEN 4096
#define HID   2048
#define NBLK  256
#define NTHR  512   // 8 waves/block, 1 block/CU

typedef unsigned long long u64;
typedef float v2f __attribute__((ext_vector_type(2)));
typedef unsigned int v4u __attribute__((ext_vector_type(4)));

// R7 = R4 structure (tagged-data dataflow, single publish burst, wave-0 cell math,
// two block syncs) + SOFTWARE-PIPELINED POLLING:
//  - two poll batches in flight; s_waitcnt vmcnt(2) waits only the older batch ->
//    retry round ~RTT/2 instead of full RTT. Loads live inside inline asm so the
//    compiler inserts no extra vmcnt; register ties order the tag checks after the
//    wait. Monotone tags (stale < want, 0xAA poison never matches) make any stale
//    register read a harmless extra round, never a false match.
//  - vmcnt(0) drain with register binds at loop exit so in-flight loads can't
//    clobber reallocated registers.
//  - single publish (replicas removed — R6's producer-side commit serialization).
//  - 16B paired polls (entries 2l,2l+1 adjacent), packed v_pk_fma_f32, fast
//    activations (all correctness-validated in R5/R6; absmax 1.2e-4).

__device__ __forceinline__ float fsig(float x) {
    return 1.0f / (1.0f + __expf(-x));
}
__device__ __forceinline__ float ftanh(float x) {
    float e = __expf(2.0f * fabsf(x));       // >=1; inf for large |x| -> r = 1
    float r = 1.0f - 2.0f / (e + 1.0f);
    return copysignf(r, x);
}

// issue two agent-scope (L1+L2 bypass) 16B loads covering 4 tagged entries; NO wait
#define POLL_ISSUE(Ra, Rb)                                         \
    asm volatile("global_load_dwordx4 %0, %2, off sc0 sc1\n\t"     \
                 "global_load_dwordx4 %1, %3, off sc0 sc1"         \
                 : "=&v"(Ra), "=&v"(Rb) : "v"(p0), "v"(p1) : "memory")

// wait until only the newest batch (2 loads) is still in flight; bind regs so the
// subsequent tag checks consume post-wait values
#define POLL_WAIT2(Ra, Rb)                                         \
    asm volatile("s_waitcnt vmcnt(2)" : "+v"(Ra), "+v"(Rb))

__global__ __launch_bounds__(NTHR, 2)
void qlstm_persistent(const float* __restrict__ inp,     // (S,1,4)
                      const float* __restrict__ conv_w,  // (4)
                      const float* __restrict__ conv_b,  // (1)
                      const float* __restrict__ Wg,      // (2049, 8192) row-major
                      const float* __restrict__ bg,      // (8192)
                      float* __restrict__ out,           // S*H + H + H
                      float* __restrict__ ws)            // scratch (poison 0xAA ok)
{
    const int b   = blockIdx.x;
    const int tid = threadIdx.x;
    const int l   = tid & 63;
    const int wv  = tid >> 6;

    u64* tb0 = (u64*)ws;            // [HID] tagged hx, parity 0
    u64* tb1 = tb0 + HID + 16;      // [HID] tagged hx, parity 1 (line-padded)

    __shared__ __align__(16) float hx_lds[HID];
    __shared__ __align__(16) float conv_lds[S_LEN];
    __shared__ float gates_lds[32];

    // ---------------- init phase ----------------
    {
        const float cw0 = conv_w[0], cw1 = conv_w[1], cw2 = conv_w[2], cw3 = conv_w[3];
        const float cb  = conv_b[0];
        for (int g = tid; g < S_LEN; g += NTHR) {
            float4 x = ((const float4*)inp)[g];
            conv_lds[g] = fsig(x.x*cw0 + x.y*cw1 + x.z*cw2 + x.w*cw3 + cb);
        }
    }

    // wave wv owns gate columns cgi = 4wv+c; cgi -> gate = cgi>>3, unit mi = cgi&7
    int jcol[4];
    #pragma unroll
    for (int c = 0; c < 4; ++c) {
        int cgi  = 4*wv + c;
        jcol[c]  = ((cgi >> 3) << 11) + (b * 8 + (cgi & 7));
    }

    // cell-phase constants (meaningful in lanes tid<8)
    float cw_reg[4], cb_reg[4];
    {
        int u8 = b * 8 + (tid & 7);
        #pragma unroll
        for (int c = 0; c < 4; ++c) {
            cw_reg[c] = Wg[(c << 11) + u8];
            cb_reg[c] = bg[(c << 11) + u8];
        }
    }

    // persistent packed W: lane l consumes hx elements 4l+256j+r (j=0..7, r=0..3)
    // wreg2[c][2j+p] = { W[1+4l+256j+2p][jcol[c]], W[1+4l+256j+2p+1][jcol[c]] }
    v2f wreg2[4][16];
    #pragma unroll
    for (int j = 0; j < 8; ++j)
        #pragma unroll
        for (int p = 0; p < 2; ++p) {
            const float* r0 = Wg + (size_t)(1 + 4*l + 256*j + 2*p) * 8192;
            const float* r1 = r0 + 8192;
            #pragma unroll
            for (int c = 0; c < 4; ++c)
                wreg2[c][2*j + p] = (v2f){ r0[jcol[c]], r1[jcol[c]] };
        }

    float cx = 0.0f;                       // live in lanes tid<8
    const int unit = b * 8 + (tid & 7);    // hidden unit for tid<8

    // publish hx_0 = 0 with tag 1 (single 8B atomic; tag travels with value)
    if (tid < 8)
        __hip_atomic_store(&tb0[unit], (u64)1 << 32,
                           __ATOMIC_RELAXED, __HIP_MEMORY_SCOPE_AGENT);

    const int pairoff = (wv << 8) + 2*l;   // entries pairoff..+1 and +128..+129

    // ---------------- recurrence ----------------
    for (int t = 0; t < S_LEN; ++t) {
        const unsigned want = (unsigned)(t + 1);
        const u64* base = (t & 1) ? tb1 : tb0;  // hx_t lives here, tag t+1
        u64*       nbuf = (t & 1) ? tb0 : tb1;  // hx_{t+1} goes here, tag t+2
        const u64* p0 = base + pairoff;
        const u64* p1 = base + pairoff + 128;

        // --- pipelined poll: 2 batches x 2x16B, round ~ RTT/2 ---
        v4u A0, A1, B0, B1;
        POLL_ISSUE(A0, A1);
        POLL_ISSUE(B0, B1);
        unsigned r0, r1, r2, r3;
        for (;;) {
            POLL_WAIT2(A0, A1);            // batch A complete (B still in flight)
            if (A0.y == want && A0.w == want && A1.y == want && A1.w == want) {
                r0 = A0.x; r1 = A0.z; r2 = A1.x; r3 = A1.z; break;
            }
            POLL_ISSUE(A0, A1);
            POLL_WAIT2(B0, B1);            // batch B complete (A' in flight)
            if (B0.y == want && B0.w == want && B1.y == want && B1.w == want) {
                r0 = B0.x; r1 = B0.z; r2 = B1.x; r3 = B1.z; break;
            }
            POLL_ISSUE(B0, B1);
        }
        // drain the still-in-flight batch before its registers can be reused
        asm volatile("s_waitcnt vmcnt(0)"
                     : "+v"(A0), "+v"(A1), "+v"(B0), "+v"(B1) :: "memory");

        ((float2*)hx_lds)[(wv << 7) + l] =
            (float2){ __uint_as_float(r0), __uint_as_float(r1) };
        ((float2*)hx_lds)[(wv << 7) + 64 + l] =
            (float2){ __uint_as_float(r2), __uint_as_float(r3) };
        __syncthreads();                       // A: hx_lds complete

        const float4* hl = (const float4*)hx_lds;
        v2f a0 = {0.f, 0.f}, a1 = {0.f, 0.f}, a2 = {0.f, 0.f}, a3 = {0.f, 0.f};
        #pragma unroll
        for (int j = 0; j < 8; ++j) {
            float4 h = hl[l + 64*j];           // ds_read_b128, conflict-free
            v2f h01 = { h.x, h.y };
            v2f h23 = { h.z, h.w };
            a0 = __builtin_elementwise_fma(h01, wreg2[0][2*j  ], a0);
            a1 = __builtin_elementwise_fma(h01, wreg2[1][2*j  ], a1);
            a2 = __builtin_elementwise_fma(h01, wreg2[2][2*j  ], a2);
            a3 = __builtin_elementwise_fma(h01, wreg2[3][2*j  ], a3);
            a0 = __builtin_elementwise_fma(h23, wreg2[0][2*j+1], a0);
            a1 = __builtin_elementwise_fma(h23, wreg2[1][2*j+1], a1);
            a2 = __builtin_elementwise_fma(h23, wreg2[2][2*j+1], a2);
            a3 = __builtin_elementwise_fma(h23, wreg2[3][2*j+1], a3);
        }
        float acc0 = a0.x + a0.y;
        float acc1 = a1.x + a1.y;
        float acc2 = a2.x + a2.y;
        float acc3 = a3.x + a3.y;
        #pragma unroll
        for (int off = 32; off; off >>= 1) {
            acc0 += __shfl_down(acc0, off, 64);
            acc1 += __shfl_down(acc1, off, 64);
            acc2 += __shfl_down(acc2, off, 64);
            acc3 += __shfl_down(acc3, off, 64);
        }
        if (l == 0) {
            gates_lds[4*wv + 0] = acc0;
            gates_lds[4*wv + 1] = acc1;
            gates_lds[4*wv + 2] = acc2;
            gates_lds[4*wv + 3] = acc3;
        }
        __syncthreads();                       // B: gates complete
        // waves 1..7 proceed straight to polling step t+1

        if (tid < 8) {
            float ct = conv_lds[t];
            float f  = fsig (gates_lds[tid]      + ct*cw_reg[0] + cb_reg[0]);
            float ii = fsig (gates_lds[8 + tid]  + ct*cw_reg[1] + cb_reg[1]);
            float gv = ftanh(gates_lds[16 + tid] + ct*cw_reg[2] + cb_reg[2]);
            float o  = fsig (gates_lds[24 + tid] + ct*cw_reg[3] + cb_reg[3]);
            cx = f * cx + ii * gv;
            float hx = o * ftanh(cx);
            // publish: one 8B atomic per lane, 8 lanes -> one 64B burst
            __hip_atomic_store(&nbuf[unit],
                               ((u64)(unsigned)(t + 2) << 32) | (u64)__float_as_uint(hx),
                               __ATOMIC_RELAXED, __HIP_MEMORY_SCOPE_AGENT);
            // out[] store off the critical path (after the publish)
            out[(size_t)t * HID + unit] = hx;
            if (t == S_LEN - 1) {
                out[(size_t)S_LEN * HID + unit]       = hx;   // final hx
                out[(size_t)S_LEN * HID + HID + unit] = cx;   // final cx
            }
        }
    }
}

extern "C" void kernel_launch(void* const* d_in, const int* in_sizes, int n_in,
                              void* d_out, int out_size, void* d_ws, size_t ws_size,
                              hipStream_t stream) {
    const float* inp    = (const float*)d_in[0];
    const float* conv_w = (const float*)d_in[1];
    const float* conv_b = (const float*)d_in[2];
    const float* Wg     = (const float*)d_in[3];
    const float* bg     = (const float*)d_in[4];
    float* out = (float*)d_out;
    float* ws  = (float*)d_ws;

    // no memset needed: exact-match tags (1..4097) can never alias 0xAA poison

    void* args[] = {(void*)&inp, (void*)&conv_w, (void*)&conv_b,
                    (void*)&Wg, (void*)&bg, (void*)&out, (void*)&ws};
    hipLaunchCooperativeKernel((void*)qlstm_persistent,
                               dim3(NBLK), dim3(NTHR), args, 0, stream);
}